// Round 8
// baseline (429.155 us; speedup 1.0000x reference)
//
#include <hip/hip_runtime.h>
#include <stdint.h>
#include <math.h>

#define D      2048
#define E      64
#define ROWS   16384
#define RB     128       // rows per block (lane owns 2 rows: lane, lane+64)
#define BK     32        // k per chunk
#define EW     16        // experts per wave
#define NSPLIT 8
#define NCH    ((D / NSPLIT) / BK)   // 8

typedef const __attribute__((address_space(1))) unsigned int guint;
typedef __attribute__((address_space(3))) unsigned int luint;

__device__ __forceinline__ void gl_lds16(const float* g, float* l) {
    __builtin_amdgcn_global_load_lds((guint*)g, (luint*)l, 16, 0, 0);
}

// ---------------- kernel 1: logits partials ----------------
// grid = 128 row-groups x 8 k-splits = 1024 blocks, 256 threads, 32KB LDS,
// VGPR<=128 -> 4 blocks/CU = 4 waves/SIMD (TLP hides W-load + stage latency).
// Wave w owns experts w*16..+15; lane owns rows {lane, lane+64}.
// X: LDS double-buffered, quad-swizzled (q ^= row&7), per-lane b128 reads.
// W: direct from Wr, 16 hoisted uniform VGPR pointers + imm offsets.
__global__ __launch_bounds__(256, 4)
void logits_kernel(const float* __restrict__ x, const float* __restrict__ Wr,
                   float* __restrict__ P) {
    __shared__ float XS[2][RB * BK];   // 2 x 16 KB

    const int tid  = threadIdx.x;
    const int lane = tid & 63;
    const int wu   = __builtin_amdgcn_readfirstlane(tid >> 6);
    const int bid  = blockIdx.x;
    const int ks   = bid % NSPLIT;
    const int rg   = bid / NSPLIT;
    const int row0 = rg * RB;
    const int kb   = ks * (D / NSPLIT);

    // forced-vector zero: keeps W addresses in VGPRs (no scalarization)
    int vz;
    asm volatile("v_mov_b32 %0, 0" : "=v"(vz));

    // staging: inst i, thread t -> dest float off = i*1024 + t*4
    //   dest row = i*32 + (t>>3); dest quad = t&7 holds src quad (t&7)^(row&7)
    //   => LDS[r][q] = x quad q ^ (r&7)
    const float* const xstage =
        x + (size_t)(row0 + (tid >> 3)) * D + kb + ((((tid & 7) ^ ((tid >> 3) & 7))) << 2);
    float* const xsl0 = &XS[0][tid * 4];
    float* const xsl1 = &XS[1][tid * 4];

#define STAGE(b, cc) do {                                                     \
        _Pragma("unroll")                                                     \
        for (int i = 0; i < 4; ++i)                                           \
            gl_lds16(xstage + (size_t)(cc) * BK + (size_t)i * 32 * D,         \
                     ((b) ? xsl1 : xsl0) + i * 1024);                         \
    } while (0)

    const int eb = wu * EW;
    const float* we[EW];
#pragma unroll
    for (int e = 0; e < EW; ++e)
        we[e] = Wr + (size_t)(eb + e) * D + kb + vz;

    float acc[2][EW];
#pragma unroll
    for (int j = 0; j < 2; ++j)
#pragma unroll
        for (int e = 0; e < EW; ++e) acc[j][e] = 0.0f;

    STAGE(0, 0);

    const int swq = (lane & 7) << 2;   // read-side quad swizzle (float units)
    int cur = 0;
    for (int c = 0; c < NCH; ++c) {
        asm volatile("s_waitcnt vmcnt(0)" ::: "memory");
        __syncthreads();
        if (c + 1 < NCH) STAGE(cur ^ 1, c + 1);

        const float* const xb = &XS[cur][0];
#pragma unroll
        for (int kq = 0; kq < 8; ++kq) {
            float4 xq[2];
#pragma unroll
            for (int j = 0; j < 2; ++j)
                xq[j] = *(const float4*)(xb + (64 * j + lane) * BK + ((kq << 2) ^ swq));
#pragma unroll
            for (int e = 0; e < EW; ++e) {
                const float4 wv = *(const float4*)(we[e] + c * BK + kq * 4);
#pragma unroll
                for (int j = 0; j < 2; ++j) {
                    acc[j][e] = fmaf(xq[j].x, wv.x, acc[j][e]);
                    acc[j][e] = fmaf(xq[j].y, wv.y, acc[j][e]);
                    acc[j][e] = fmaf(xq[j].z, wv.z, acc[j][e]);
                    acc[j][e] = fmaf(xq[j].w, wv.w, acc[j][e]);
                }
            }
        }
        cur ^= 1;
    }

    // partial store: P[ks][row][e]
#pragma unroll
    for (int j = 0; j < 2; ++j) {
        float* const pr = P + ((size_t)ks * ROWS + row0 + 64 * j + lane) * E + eb;
#pragma unroll
        for (int g = 0; g < 4; ++g)
            *(float4*)(pr + 4 * g) = make_float4(acc[j][4 * g + 0], acc[j][4 * g + 1],
                                                 acc[j][4 * g + 2], acc[j][4 * g + 3]);
    }
#undef STAGE
}

// ---------------- kernel 2: reduce + softmax + top-2 ----------------
template<int NS>
__global__ __launch_bounds__(256, 8)
void finish_kernel(const float* __restrict__ P, float* __restrict__ out) {
    const int lane = threadIdx.x & 63;
    const int w    = threadIdx.x >> 6;
    const int row  = blockIdx.x * 4 + w;

    float v = 0.0f;
#pragma unroll
    for (int s = 0; s < NS; ++s)
        v += P[((size_t)s * ROWS + row) * E + lane];

    float* const out_gw    = out;               // [16384][2]
    float* const out_idx   = out + 32768;       // [16384][2] (indices as floats)
    float* const out_probs = out + 65536;       // [16384][64]

    float m = v;
#pragma unroll
    for (int off = 32; off; off >>= 1) m = fmaxf(m, __shfl_xor(m, off));
    const float p = __expf(v - m);
    float s = p;
#pragma unroll
    for (int off = 32; off; off >>= 1) s += __shfl_xor(s, off);
    const float inv_s = 1.0f / s;

    out_probs[(size_t)row * 64 + lane] = p * inv_s;

    float v1 = v; int i1 = lane;
#pragma unroll
    for (int off = 32; off; off >>= 1) {
        const float ov = __shfl_xor(v1, off);
        const int   oi = __shfl_xor(i1, off);
        if (ov > v1 || (ov == v1 && oi < i1)) { v1 = ov; i1 = oi; }
    }
    float v2 = (lane == i1) ? -INFINITY : v; int i2 = lane;
#pragma unroll
    for (int off = 32; off; off >>= 1) {
        const float ov = __shfl_xor(v2, off);
        const int   oi = __shfl_xor(i2, off);
        if (ov > v2 || (ov == v2 && oi < i2)) { v2 = ov; i2 = oi; }
    }

    if (lane == 0) {
        const float p1 = __expf(v1 - m) * inv_s;
        const float p2 = __expf(v2 - m) * inv_s;
        const float inv12 = 1.0f / (p1 + p2);
        out_gw[(size_t)row * 2 + 0]  = p1 * inv12;
        out_gw[(size_t)row * 2 + 1]  = p2 * inv12;
        out_idx[(size_t)row * 2 + 0] = (float)i1;
        out_idx[(size_t)row * 2 + 1] = (float)i2;
    }
}

// fallback single-split logits (small ws): same structure, NSPLIT folded to 1
__global__ __launch_bounds__(256, 4)
void logits_kernel_ns1(const float* __restrict__ x, const float* __restrict__ Wr,
                       float* __restrict__ P) {
    __shared__ float XS[2][RB * BK];
    const int tid  = threadIdx.x;
    const int lane = tid & 63;
    const int wu   = __builtin_amdgcn_readfirstlane(tid >> 6);
    const int row0 = blockIdx.x * RB;
    int vz;
    asm volatile("v_mov_b32 %0, 0" : "=v"(vz));
    const float* const xstage =
        x + (size_t)(row0 + (tid >> 3)) * D + ((((tid & 7) ^ ((tid >> 3) & 7))) << 2);
    float* const xsl0 = &XS[0][tid * 4];
    float* const xsl1 = &XS[1][tid * 4];
    const int eb = wu * EW;
    const float* we[EW];
#pragma unroll
    for (int e = 0; e < EW; ++e) we[e] = Wr + (size_t)(eb + e) * D + vz;
    float acc[2][EW];
#pragma unroll
    for (int j = 0; j < 2; ++j)
#pragma unroll
        for (int e = 0; e < EW; ++e) acc[j][e] = 0.0f;
#pragma unroll
    for (int i = 0; i < 4; ++i)
        gl_lds16(xstage + (size_t)i * 32 * D, xsl0 + i * 1024);
    const int swq = (lane & 7) << 2;
    int cur = 0;
    for (int c = 0; c < D / BK; ++c) {
        asm volatile("s_waitcnt vmcnt(0)" ::: "memory");
        __syncthreads();
        if (c + 1 < D / BK) {
#pragma unroll
            for (int i = 0; i < 4; ++i)
                gl_lds16(xstage + (size_t)(c + 1) * BK + (size_t)i * 32 * D,
                         (cur ? xsl0 : xsl1) + i * 1024);
        }
        const float* const xb = &XS[cur][0];
#pragma unroll
        for (int kq = 0; kq < 8; ++kq) {
            float4 xq[2];
#pragma unroll
            for (int j = 0; j < 2; ++j)
                xq[j] = *(const float4*)(xb + (64 * j + lane) * BK + ((kq << 2) ^ swq));
#pragma unroll
            for (int e = 0; e < EW; ++e) {
                const float4 wv = *(const float4*)(we[e] + c * BK + kq * 4);
#pragma unroll
                for (int j = 0; j < 2; ++j) {
                    acc[j][e] = fmaf(xq[j].x, wv.x, acc[j][e]);
                    acc[j][e] = fmaf(xq[j].y, wv.y, acc[j][e]);
                    acc[j][e] = fmaf(xq[j].z, wv.z, acc[j][e]);
                    acc[j][e] = fmaf(xq[j].w, wv.w, acc[j][e]);
                }
            }
        }
        cur ^= 1;
    }
#pragma unroll
    for (int j = 0; j < 2; ++j) {
        float* const pr = P + ((size_t)row0 + 64 * j + lane) * E + eb;
#pragma unroll
        for (int g = 0; g < 4; ++g)
            *(float4*)(pr + 4 * g) = make_float4(acc[j][4 * g + 0], acc[j][4 * g + 1],
                                                 acc[j][4 * g + 2], acc[j][4 * g + 3]);
    }
}

extern "C" void kernel_launch(void* const* d_in, const int* in_sizes, int n_in,
                              void* d_out, int out_size, void* d_ws, size_t ws_size,
                              hipStream_t stream) {
    const float* x  = (const float*)d_in[0];
    const float* Wr = (const float*)d_in[1];
    float* out = (float*)d_out;
    float* P   = (float*)d_ws;

    const size_t perSplit = (size_t)ROWS * E * sizeof(float);   // 4.19 MB
    if (ws_size >= NSPLIT * perSplit) {
        hipLaunchKernelGGL(logits_kernel, dim3((ROWS / RB) * NSPLIT), dim3(256), 0, stream, x, Wr, P);
        hipLaunchKernelGGL((finish_kernel<NSPLIT>), dim3(ROWS / 4), dim3(256), 0, stream, P, out);
    } else {
        hipLaunchKernelGGL(logits_kernel_ns1, dim3(ROWS / RB), dim3(256), 0, stream, x, Wr, P);
        hipLaunchKernelGGL((finish_kernel<1>), dim3(ROWS / 4), dim3(256), 0, stream, P, out);
    }
}

// Round 9
// 147.009 us; speedup vs baseline: 2.9192x; 2.9192x over previous
//
#include <hip/hip_runtime.h>
#include <stdint.h>
#include <math.h>

#define D      2048
#define E      64
#define ROWS   16384
#define RB     128       // rows per block (lane owns 2 rows: lane, lane+64)
#define BK     32        // k per chunk
#define EW     16        // experts per wave
#define NSPLIT 8
#define NCH    ((D / NSPLIT) / BK)   // 8

typedef const __attribute__((address_space(1))) unsigned int guint;
typedef __attribute__((address_space(3))) unsigned int luint;

__device__ __forceinline__ void gl_lds16(const float* g, float* l) {
    __builtin_amdgcn_global_load_lds((guint*)g, (luint*)l, 16, 0, 0);
}

// ---------------- kernel 1: logits partials ----------------
// grid = 128 row-groups x 8 k-splits = 1024 blocks, 256 threads, 32KB LDS.
// No launch_bounds minimum: R8's (256,4) made the allocator clamp to 64
// VGPRs and spill (793MB scratch writes). Demand here ~70 VGPRs -> 4 blk/CU.
// Wave w owns experts w*16..+15; lane owns rows {lane, lane+64}.
// X: LDS double-buffered, quad-swizzled (q ^= r&7), per-lane b128 reads.
// W: SGPR-base + vz vector-offset global_load_dwordx4 (bases live in SGPRs,
//    offsets fold to 13-bit imm; VMEM-pipelined, no scalar-pipe stall).
__global__ __launch_bounds__(256)
void logits_kernel(const float* __restrict__ x, const float* __restrict__ Wr,
                   float* __restrict__ P) {
    __shared__ float XS[2][RB * BK];   // 2 x 16 KB

    const int tid  = threadIdx.x;
    const int lane = tid & 63;
    const int wu   = __builtin_amdgcn_readfirstlane(tid >> 6);
    const int bid  = blockIdx.x;
    const int ks   = bid % NSPLIT;
    const int rg   = bid / NSPLIT;
    const int row0 = rg * RB;
    const int kb   = ks * (D / NSPLIT);

    // asm-opaque vector zero: forces the W-load OFFSET into a VGPR while the
    // base stays scalar -> global_load_dwordx4 v, v_off, s[base:base+1]
    int vz;
    asm volatile("v_mov_b32 %0, 0" : "=v"(vz));

    // staging: inst i, thread t -> dest float off = i*1024 + t*4
    //   dest row = i*32 + (t>>3); dest quad = t&7 holds src quad (t&7)^(row&7)
    //   => LDS[r][q] = x quad q ^ (r&7)
    const float* const xstage =
        x + (size_t)(row0 + (tid >> 3)) * D + kb + ((((tid & 7) ^ ((tid >> 3) & 7))) << 2);
    float* const xsl0 = &XS[0][tid * 4];
    float* const xsl1 = &XS[1][tid * 4];

#define STAGE(b, cc) do {                                                     \
        _Pragma("unroll")                                                     \
        for (int i = 0; i < 4; ++i)                                           \
            gl_lds16(xstage + (size_t)(cc) * BK + (size_t)i * 32 * D,         \
                     ((b) ? xsl1 : xsl0) + i * 1024);                         \
    } while (0)

    const int eb = wu * EW;

    float acc[2][EW];
#pragma unroll
    for (int j = 0; j < 2; ++j)
#pragma unroll
        for (int e = 0; e < EW; ++e) acc[j][e] = 0.0f;

    STAGE(0, 0);

    const int swq = (lane & 7) << 2;   // read-side quad swizzle (float units)
    int cur = 0;
    for (int c = 0; c < NCH; ++c) {
        asm volatile("s_waitcnt vmcnt(0)" ::: "memory");
        __syncthreads();
        if (c + 1 < NCH) STAGE(cur ^ 1, c + 1);

        const float* const xb = &XS[cur][0];
#pragma unroll
        for (int kq = 0; kq < 8; ++kq) {
            float4 xq[2];
#pragma unroll
            for (int j = 0; j < 2; ++j)
                xq[j] = *(const float4*)(xb + (64 * j + lane) * BK + ((kq << 2) ^ swq));
#pragma unroll
            for (int e = 0; e < EW; ++e) {
                // scalar base (SGPR pair, hoisted per e) + vector offset vz + imm
                const float* const wbase = Wr + (size_t)(eb + e) * D + kb;  // scalar
                const float4 wv = *(const float4*)(wbase + vz + c * BK + kq * 4);
#pragma unroll
                for (int j = 0; j < 2; ++j) {
                    acc[j][e] = fmaf(xq[j].x, wv.x, acc[j][e]);
                    acc[j][e] = fmaf(xq[j].y, wv.y, acc[j][e]);
                    acc[j][e] = fmaf(xq[j].z, wv.z, acc[j][e]);
                    acc[j][e] = fmaf(xq[j].w, wv.w, acc[j][e]);
                }
            }
        }
        cur ^= 1;
    }

    // partial store: P[ks][row][e] (each lane writes one full 64B line)
#pragma unroll
    for (int j = 0; j < 2; ++j) {
        float* const pr = P + ((size_t)ks * ROWS + row0 + 64 * j + lane) * E + eb;
#pragma unroll
        for (int g = 0; g < 4; ++g)
            *(float4*)(pr + 4 * g) = make_float4(acc[j][4 * g + 0], acc[j][4 * g + 1],
                                                 acc[j][4 * g + 2], acc[j][4 * g + 3]);
    }
#undef STAGE
}

// ---------------- kernel 2: reduce + softmax + top-2 ----------------
template<int NS>
__global__ __launch_bounds__(256)
void finish_kernel(const float* __restrict__ P, float* __restrict__ out) {
    const int lane = threadIdx.x & 63;
    const int w    = threadIdx.x >> 6;
    const int row  = blockIdx.x * 4 + w;

    float v = 0.0f;
#pragma unroll
    for (int s = 0; s < NS; ++s)
        v += P[((size_t)s * ROWS + row) * E + lane];

    float* const out_gw    = out;               // [16384][2]
    float* const out_idx   = out + 32768;       // [16384][2] (indices as floats)
    float* const out_probs = out + 65536;       // [16384][64]

    float m = v;
#pragma unroll
    for (int off = 32; off; off >>= 1) m = fmaxf(m, __shfl_xor(m, off));
    const float p = __expf(v - m);
    float s = p;
#pragma unroll
    for (int off = 32; off; off >>= 1) s += __shfl_xor(s, off);
    const float inv_s = 1.0f / s;

    out_probs[(size_t)row * 64 + lane] = p * inv_s;

    float v1 = v; int i1 = lane;
#pragma unroll
    for (int off = 32; off; off >>= 1) {
        const float ov = __shfl_xor(v1, off);
        const int   oi = __shfl_xor(i1, off);
        if (ov > v1 || (ov == v1 && oi < i1)) { v1 = ov; i1 = oi; }
    }
    float v2 = (lane == i1) ? -INFINITY : v; int i2 = lane;
#pragma unroll
    for (int off = 32; off; off >>= 1) {
        const float ov = __shfl_xor(v2, off);
        const int   oi = __shfl_xor(i2, off);
        if (ov > v2 || (ov == v2 && oi < i2)) { v2 = ov; i2 = oi; }
    }

    if (lane == 0) {
        const float p1 = __expf(v1 - m) * inv_s;
        const float p2 = __expf(v2 - m) * inv_s;
        const float inv12 = 1.0f / (p1 + p2);
        out_gw[(size_t)row * 2 + 0]  = p1 * inv12;
        out_gw[(size_t)row * 2 + 1]  = p2 * inv12;
        out_idx[(size_t)row * 2 + 0] = (float)i1;
        out_idx[(size_t)row * 2 + 1] = (float)i2;
    }
}

// fallback single-split logits (small ws): same structure, NSPLIT folded to 1
__global__ __launch_bounds__(256)
void logits_kernel_ns1(const float* __restrict__ x, const float* __restrict__ Wr,
                       float* __restrict__ P) {
    __shared__ float XS[2][RB * BK];
    const int tid  = threadIdx.x;
    const int lane = tid & 63;
    const int wu   = __builtin_amdgcn_readfirstlane(tid >> 6);
    const int row0 = blockIdx.x * RB;
    int vz;
    asm volatile("v_mov_b32 %0, 0" : "=v"(vz));
    const float* const xstage =
        x + (size_t)(row0 + (tid >> 3)) * D + ((((tid & 7) ^ ((tid >> 3) & 7))) << 2);
    float* const xsl0 = &XS[0][tid * 4];
    float* const xsl1 = &XS[1][tid * 4];
    const int eb = wu * EW;
    float acc[2][EW];
#pragma unroll
    for (int j = 0; j < 2; ++j)
#pragma unroll
        for (int e = 0; e < EW; ++e) acc[j][e] = 0.0f;
#pragma unroll
    for (int i = 0; i < 4; ++i)
        gl_lds16(xstage + (size_t)i * 32 * D, xsl0 + i * 1024);
    const int swq = (lane & 7) << 2;
    int cur = 0;
    for (int c = 0; c < D / BK; ++c) {
        asm volatile("s_waitcnt vmcnt(0)" ::: "memory");
        __syncthreads();
        if (c + 1 < D / BK) {
#pragma unroll
            for (int i = 0; i < 4; ++i)
                gl_lds16(xstage + (size_t)(c + 1) * BK + (size_t)i * 32 * D,
                         (cur ? xsl0 : xsl1) + i * 1024);
        }
        const float* const xb = &XS[cur][0];
#pragma unroll
        for (int kq = 0; kq < 8; ++kq) {
            float4 xq[2];
#pragma unroll
            for (int j = 0; j < 2; ++j)
                xq[j] = *(const float4*)(xb + (64 * j + lane) * BK + ((kq << 2) ^ swq));
#pragma unroll
            for (int e = 0; e < EW; ++e) {
                const float* const wbase = Wr + (size_t)(eb + e) * D;  // scalar
                const float4 wv = *(const float4*)(wbase + vz + c * BK + kq * 4);
#pragma unroll
                for (int j = 0; j < 2; ++j) {
                    acc[j][e] = fmaf(xq[j].x, wv.x, acc[j][e]);
                    acc[j][e] = fmaf(xq[j].y, wv.y, acc[j][e]);
                    acc[j][e] = fmaf(xq[j].z, wv.z, acc[j][e]);
                    acc[j][e] = fmaf(xq[j].w, wv.w, acc[j][e]);
                }
            }
        }
        cur ^= 1;
    }
#pragma unroll
    for (int j = 0; j < 2; ++j) {
        float* const pr = P + ((size_t)row0 + 64 * j + lane) * E + eb;
#pragma unroll
        for (int g = 0; g < 4; ++g)
            *(float4*)(pr + 4 * g) = make_float4(acc[j][4 * g + 0], acc[j][4 * g + 1],
                                                 acc[j][4 * g + 2], acc[j][4 * g + 3]);
    }
}

extern "C" void kernel_launch(void* const* d_in, const int* in_sizes, int n_in,
                              void* d_out, int out_size, void* d_ws, size_t ws_size,
                              hipStream_t stream) {
    const float* x  = (const float*)d_in[0];
    const float* Wr = (const float*)d_in[1];
    float* out = (float*)d_out;
    float* P   = (float*)d_ws;

    const size_t perSplit = (size_t)ROWS * E * sizeof(float);   // 4.19 MB
    if (ws_size >= NSPLIT * perSplit) {
        hipLaunchKernelGGL(logits_kernel, dim3((ROWS / RB) * NSPLIT), dim3(256), 0, stream, x, Wr, P);
        hipLaunchKernelGGL((finish_kernel<NSPLIT>), dim3(ROWS / 4), dim3(256), 0, stream, P, out);
    } else {
        hipLaunchKernelGGL(logits_kernel_ns1, dim3(ROWS / RB), dim3(256), 0, stream, x, Wr, P);
        hipLaunchKernelGGL((finish_kernel<1>), dim3(ROWS / 4), dim3(256), 0, stream, P, out);
    }
}

// Round 10
// 123.843 us; speedup vs baseline: 3.4653x; 1.1871x over previous
//
#include <hip/hip_runtime.h>
#include <stdint.h>
#include <math.h>

#define D      2048
#define E      64
#define ROWS   16384
#define RB     256       // rows per block (lane owns 4 rows: lane + 64j)
#define BK     64        // k per superchunk (staged whole before compute)
#define EW     16        // experts per wave
#define NSPLIT 8
#define NCH    ((D / NSPLIT) / BK)   // 4

typedef const __attribute__((address_space(1))) unsigned int guint;
typedef __attribute__((address_space(3))) unsigned int luint;

__device__ __forceinline__ void gl_lds16(const float* g, float* l) {
    __builtin_amdgcn_global_load_lds((guint*)g, (luint*)l, 16, 0, 0);
}

// ---------------- kernel 1: logits partials ----------------
// grid = 64 row-groups x 8 k-splits = 512 blocks, 256 threads, 64KB LDS
// -> 2 blocks/CU. Key structural fix vs R9: X-stage completes (vmcnt(0) +
// barrier) BEFORE compute begins, so the in-order vmcnt stream during
// compute contains ONLY W loads -> W pipelining never blocks on HBM staging.
// Wave w owns experts w*16..+15; lane owns rows {lane+64j, j=0..3}.
// X: 64KB superchunk, quad-swizzled (q ^= r&15), per-lane b128 (0-conflict,
// measured R7). W: SGPR-base + vz vector-offset, imm-folded (R9-proven).
__global__ __launch_bounds__(256)
void logits_kernel(const float* __restrict__ x, const float* __restrict__ Wr,
                   float* __restrict__ P) {
    __shared__ float XS[RB * BK];   // 64 KB, single buffer

    const int tid  = threadIdx.x;
    const int lane = tid & 63;
    const int wu   = __builtin_amdgcn_readfirstlane(tid >> 6);
    const int bid  = blockIdx.x;
    const int ks   = bid % NSPLIT;
    const int rg   = bid / NSPLIT;
    const int row0 = rg * RB;
    const int kb   = ks * (D / NSPLIT);

    // asm-opaque vector zero: W-load offset lives in a VGPR, base in SGPRs
    int vz;
    asm volatile("v_mov_b32 %0, 0" : "=v"(vz));

    // staging: inst i, thread t -> dest float off = i*1024 + t*4
    //   dest row = i*16 + (t>>4); dest quad (t&15) holds src quad (t&15)^(t>>4)
    //   => LDS[r][q] = x quad q ^ (r&15)
    const float* const xstage =
        x + (size_t)(row0 + (tid >> 4)) * D + kb + (((tid & 15) ^ (tid >> 4)) << 2);

#define STAGE(cc) do {                                                        \
        _Pragma("unroll")                                                     \
        for (int i = 0; i < 16; ++i)                                          \
            gl_lds16(xstage + (size_t)(cc) * BK + (size_t)i * 16 * D,         \
                     &XS[i * 1024 + tid * 4]);                                \
    } while (0)

    const int eb = wu * EW;

    float acc[4][EW];
#pragma unroll
    for (int j = 0; j < 4; ++j)
#pragma unroll
        for (int e = 0; e < EW; ++e) acc[j][e] = 0.0f;

    const int swq = (lane & 15) << 2;   // read-side quad swizzle (float units)
    for (int c = 0; c < NCH; ++c) {
        STAGE(c);
        asm volatile("s_waitcnt vmcnt(0)" ::: "memory");
        __syncthreads();
        // compute phase: vmcnt stream now contains ONLY W loads
#pragma unroll
        for (int kq = 0; kq < 16; ++kq) {
            float4 xq[4];
#pragma unroll
            for (int j = 0; j < 4; ++j)
                xq[j] = *(const float4*)(&XS[(64 * j + lane) * BK + ((kq << 2) ^ swq)]);
#pragma unroll
            for (int e = 0; e < EW; ++e) {
                const float* const wbase = Wr + (size_t)(eb + e) * D + kb;  // scalar
                const float4 wv = *(const float4*)(wbase + vz + c * BK + kq * 4);
#pragma unroll
                for (int j = 0; j < 4; ++j) {
                    acc[j][e] = fmaf(xq[j].x, wv.x, acc[j][e]);
                    acc[j][e] = fmaf(xq[j].y, wv.y, acc[j][e]);
                    acc[j][e] = fmaf(xq[j].z, wv.z, acc[j][e]);
                    acc[j][e] = fmaf(xq[j].w, wv.w, acc[j][e]);
                }
            }
        }
        __syncthreads();   // all reads done before next STAGE overwrites XS
    }

    // partial store: P[ks][row][e] (each lane writes full 64B lines)
#pragma unroll
    for (int j = 0; j < 4; ++j) {
        float* const pr = P + ((size_t)ks * ROWS + row0 + 64 * j + lane) * E + eb;
#pragma unroll
        for (int g = 0; g < 4; ++g)
            *(float4*)(pr + 4 * g) = make_float4(acc[j][4 * g + 0], acc[j][4 * g + 1],
                                                 acc[j][4 * g + 2], acc[j][4 * g + 3]);
    }
#undef STAGE
}

// ---------------- kernel 2: reduce + softmax + top-2 ----------------
template<int NS>
__global__ __launch_bounds__(256)
void finish_kernel(const float* __restrict__ P, float* __restrict__ out) {
    const int lane = threadIdx.x & 63;
    const int w    = threadIdx.x >> 6;
    const int row  = blockIdx.x * 4 + w;

    float v = 0.0f;
#pragma unroll
    for (int s = 0; s < NS; ++s)
        v += P[((size_t)s * ROWS + row) * E + lane];

    float* const out_gw    = out;               // [16384][2]
    float* const out_idx   = out + 32768;       // [16384][2] (indices as floats)
    float* const out_probs = out + 65536;       // [16384][64]

    float m = v;
#pragma unroll
    for (int off = 32; off; off >>= 1) m = fmaxf(m, __shfl_xor(m, off));
    const float p = __expf(v - m);
    float s = p;
#pragma unroll
    for (int off = 32; off; off >>= 1) s += __shfl_xor(s, off);
    const float inv_s = 1.0f / s;

    out_probs[(size_t)row * 64 + lane] = p * inv_s;

    float v1 = v; int i1 = lane;
#pragma unroll
    for (int off = 32; off; off >>= 1) {
        const float ov = __shfl_xor(v1, off);
        const int   oi = __shfl_xor(i1, off);
        if (ov > v1 || (ov == v1 && oi < i1)) { v1 = ov; i1 = oi; }
    }
    float v2 = (lane == i1) ? -INFINITY : v; int i2 = lane;
#pragma unroll
    for (int off = 32; off; off >>= 1) {
        const float ov = __shfl_xor(v2, off);
        const int   oi = __shfl_xor(i2, off);
        if (ov > v2 || (ov == v2 && oi < i2)) { v2 = ov; i2 = oi; }
    }

    if (lane == 0) {
        const float p1 = __expf(v1 - m) * inv_s;
        const float p2 = __expf(v2 - m) * inv_s;
        const float inv12 = 1.0f / (p1 + p2);
        out_gw[(size_t)row * 2 + 0]  = p1 * inv12;
        out_gw[(size_t)row * 2 + 1]  = p2 * inv12;
        out_idx[(size_t)row * 2 + 0] = (float)i1;
        out_idx[(size_t)row * 2 + 1] = (float)i2;
    }
}

// fallback single-split logits (small ws): same structure, NSPLIT folded to 1
__global__ __launch_bounds__(256)
void logits_kernel_ns1(const float* __restrict__ x, const float* __restrict__ Wr,
                       float* __restrict__ P) {
    __shared__ float XS[RB * BK];
    const int tid  = threadIdx.x;
    const int lane = tid & 63;
    const int wu   = __builtin_amdgcn_readfirstlane(tid >> 6);
    const int row0 = blockIdx.x * RB;
    int vz;
    asm volatile("v_mov_b32 %0, 0" : "=v"(vz));
    const float* const xstage =
        x + (size_t)(row0 + (tid >> 4)) * D + (((tid & 15) ^ (tid >> 4)) << 2);
    const int eb = wu * EW;
    float acc[4][EW];
#pragma unroll
    for (int j = 0; j < 4; ++j)
#pragma unroll
        for (int e = 0; e < EW; ++e) acc[j][e] = 0.0f;
    const int swq = (lane & 15) << 2;
    for (int c = 0; c < D / BK; ++c) {
#pragma unroll
        for (int i = 0; i < 16; ++i)
            gl_lds16(xstage + (size_t)c * BK + (size_t)i * 16 * D,
                     &XS[i * 1024 + tid * 4]);
        asm volatile("s_waitcnt vmcnt(0)" ::: "memory");
        __syncthreads();
#pragma unroll
        for (int kq = 0; kq < 16; ++kq) {
            float4 xq[4];
#pragma unroll
            for (int j = 0; j < 4; ++j)
                xq[j] = *(const float4*)(&XS[(64 * j + lane) * BK + ((kq << 2) ^ swq)]);
#pragma unroll
            for (int e = 0; e < EW; ++e) {
                const float* const wbase = Wr + (size_t)(eb + e) * D;  // scalar
                const float4 wv = *(const float4*)(wbase + vz + c * BK + kq * 4);
#pragma unroll
                for (int j = 0; j < 4; ++j) {
                    acc[j][e] = fmaf(xq[j].x, wv.x, acc[j][e]);
                    acc[j][e] = fmaf(xq[j].y, wv.y, acc[j][e]);
                    acc[j][e] = fmaf(xq[j].z, wv.z, acc[j][e]);
                    acc[j][e] = fmaf(xq[j].w, wv.w, acc[j][e]);
                }
            }
        }
        __syncthreads();
    }
#pragma unroll
    for (int j = 0; j < 4; ++j) {
        float* const pr = P + ((size_t)row0 + 64 * j + lane) * E + eb;
#pragma unroll
        for (int g = 0; g < 4; ++g)
            *(float4*)(pr + 4 * g) = make_float4(acc[j][4 * g + 0], acc[j][4 * g + 1],
                                                 acc[j][4 * g + 2], acc[j][4 * g + 3]);
    }
}

extern "C" void kernel_launch(void* const* d_in, const int* in_sizes, int n_in,
                              void* d_out, int out_size, void* d_ws, size_t ws_size,
                              hipStream_t stream) {
    const float* x  = (const float*)d_in[0];
    const float* Wr = (const float*)d_in[1];
    float* out = (float*)d_out;
    float* P   = (float*)d_ws;

    const size_t perSplit = (size_t)ROWS * E * sizeof(float);   // 4.19 MB
    if (ws_size >= NSPLIT * perSplit) {
        hipLaunchKernelGGL(logits_kernel, dim3((ROWS / RB) * NSPLIT), dim3(256), 0, stream, x, Wr, P);
        hipLaunchKernelGGL((finish_kernel<NSPLIT>), dim3(ROWS / 4), dim3(256), 0, stream, P, out);
    } else {
        hipLaunchKernelGGL(logits_kernel_ns1, dim3(ROWS / RB), dim3(256), 0, stream, x, Wr, P);
        hipLaunchKernelGGL((finish_kernel<1>), dim3(ROWS / 4), dim3(256), 0, stream, P, out);
    }
}